// Round 14
// baseline (1482.320 us; speedup 1.0000x reference)
//
#include <hip/hip_runtime.h>
#include <stdio.h>

#define NBP   8192
#define MTOT  8192
#define CIN   64
#define C1    67
#define C1P   68
#define CO    128

#define EPR(...) do { fprintf(stderr, __VA_ARGS__); fflush(stderr); } while (0)

// ---------------------------------------------------------------------------
// Zero the 1024-float BN-stats region; write output 0 = new_xyz (f32 copy).
// ---------------------------------------------------------------------------
__global__ void __launch_bounds__(256, 1) StackSAModuleMSG_85761906966880_kernel(
    const float* __restrict__ nxyz, float* __restrict__ out, float* __restrict__ stats)
{
    int i = blockIdx.x * 256 + threadIdx.x;
    if (i < 1024) stats[i] = 0.f;
    if (i < MTOT*3) out[i] = nxyz[i];
}

// ---------------------------------------------------------------------------
// Ball query, both scales: one wave per query; f64 d2 (matches np gold).
// ---------------------------------------------------------------------------
__global__ void __launch_bounds__(64, 1) sa_ballq(
    const float* __restrict__ xyz, const float* __restrict__ new_xyz,
    int* __restrict__ idx0, int* __restrict__ idx1,
    int* __restrict__ empty0, int* __restrict__ empty1)
{
    const double r2a = 0.2 * 0.2;
    const double r2b = 0.4 * 0.4;
    int m    = blockIdx.x;
    int lane = threadIdx.x;
    int b    = m >> 11;
    int base = b * NBP;

    double nx = (double)new_xyz[3*m+0];
    double ny = (double)new_xyz[3*m+1];
    double nz = (double)new_xyz[3*m+2];
    double nn = nx*nx + ny*ny + nz*nz;

    int cnt0 = 0, cnt1 = 0;
    int first0 = base, first1 = base;
    unsigned long long lt = (1ull << lane) - 1ull;

    for (int j = 0; j < NBP; j += 64) {
        int gi = base + j + lane;
        double px = (double)xyz[3*gi+0];
        double py = (double)xyz[3*gi+1];
        double pz = (double)xyz[3*gi+2];
        double pp = px*px + py*py + pz*pz;
        double dt = nx*px + ny*py + nz*pz;
        double d2 = nn + pp - 2.0*dt;
        bool in0 = d2 < r2a;
        bool in1 = d2 < r2b;
        unsigned long long m0 = __ballot(in0);
        unsigned long long m1 = __ballot(in1);
        if (in0) {
            int p = cnt0 + __popcll(m0 & lt);
            if (p < 16) idx0[m*16 + p] = gi;
        }
        if (in1) {
            int p = cnt1 + __popcll(m1 & lt);
            if (p < 32) idx1[m*32 + p] = gi;
        }
        if (cnt0 == 0 && m0) first0 = base + j + (__ffsll((long long)m0) - 1);
        if (cnt1 == 0 && m1) first1 = base + j + (__ffsll((long long)m1) - 1);
        cnt0 += __popcll(m0);
        cnt1 += __popcll(m1);
        if (cnt0 >= 16 && cnt1 >= 32) break;
    }
    int c0 = cnt0 < 16 ? cnt0 : 16;
    int c1 = cnt1 < 32 ? cnt1 : 32;
    if (lane >= c0 && lane < 16) idx0[m*16 + lane] = first0;
    if (lane >= c1 && lane < 32) idx1[m*32 + lane] = first1;
    if (lane == 0) { empty0[m] = (cnt0 == 0); empty1[m] = (cnt1 == 0); }
}

// ---------------------------------------------------------------------------
// Pass 1: gather -> LDS, x1 = g @ W0^T -> ws, layer-1 sum/sumsq.
// 64 threads, TN=2 channels/thread (t, t+64); W0 rows in registers.
// ---------------------------------------------------------------------------
__global__ void __launch_bounds__(64, 1) sa_pass1(
    const float* __restrict__ xyz, const float* __restrict__ feat,
    const float* __restrict__ nxyz, const int* __restrict__ idx,
    const int* __restrict__ empty, const float* __restrict__ w0,
    float* __restrict__ x1, float* __restrict__ ssum, float* __restrict__ ssq,
    int NS)
{
    __shared__ float gs[32*C1P];
    __shared__ int   lidx[32];
    int m = blockIdx.x, t = threadIdx.x;
    if (t < NS) lidx[t] = idx[m*NS + t];
    __syncthreads();
    int emp = empty[m];
    for (int e = t; e < NS*C1P; e += 64) {
        int n = e / C1P, c = e - n*C1P;
        float v = 0.f;
        if (c < C1 && !emp) {
            int gi = lidx[n];
            v = (c < 3) ? (xyz[3*gi + c] - nxyz[3*m + c])
                        : feat[(long long)gi*CIN + (c-3)];
        }
        gs[e] = v;
    }
    __syncthreads();

    const float* wra = w0 + t*C1;
    const float* wrb = w0 + (t+64)*C1;
    float4 wa[17], wb[17];
#pragma unroll
    for (int c = 0; c < 16; c++) {
        wa[c] = make_float4(wra[4*c], wra[4*c+1], wra[4*c+2], wra[4*c+3]);
        wb[c] = make_float4(wrb[4*c], wrb[4*c+1], wrb[4*c+2], wrb[4*c+3]);
    }
    wa[16] = make_float4(wra[64], wra[65], wra[66], 0.f);
    wb[16] = make_float4(wrb[64], wrb[65], wrb[66], 0.f);

    float sa = 0.f, qa = 0.f, sb = 0.f, qb = 0.f;
    long long obase = (long long)m*NS*CO;
    for (int n = 0; n < NS; n++) {
        const float4* g4 = (const float4*)(gs + n*C1P);
        float a0 = 0.f, a1 = 0.f, c0 = 0.f, c1 = 0.f;
#pragma unroll
        for (int c = 0; c < 16; c += 2) {
            float4 g0 = g4[c], g1 = g4[c+1];
            a0 = fmaf(g0.x, wa[c].x,   a0); a0 = fmaf(g0.y, wa[c].y,   a0);
            a0 = fmaf(g0.z, wa[c].z,   a0); a0 = fmaf(g0.w, wa[c].w,   a0);
            c0 = fmaf(g0.x, wb[c].x,   c0); c0 = fmaf(g0.y, wb[c].y,   c0);
            c0 = fmaf(g0.z, wb[c].z,   c0); c0 = fmaf(g0.w, wb[c].w,   c0);
            a1 = fmaf(g1.x, wa[c+1].x, a1); a1 = fmaf(g1.y, wa[c+1].y, a1);
            a1 = fmaf(g1.z, wa[c+1].z, a1); a1 = fmaf(g1.w, wa[c+1].w, a1);
            c1 = fmaf(g1.x, wb[c+1].x, c1); c1 = fmaf(g1.y, wb[c+1].y, c1);
            c1 = fmaf(g1.z, wb[c+1].z, c1); c1 = fmaf(g1.w, wb[c+1].w, c1);
        }
        float4 gl = g4[16];
        a0 = fmaf(gl.x, wa[16].x, a0); a0 = fmaf(gl.y, wa[16].y, a0);
        a0 = fmaf(gl.z, wa[16].z, a0);
        c0 = fmaf(gl.x, wb[16].x, c0); c0 = fmaf(gl.y, wb[16].y, c0);
        c0 = fmaf(gl.z, wb[16].z, c0);
        float acca = a0 + a1, accb = c0 + c1;
        x1[obase + (long long)n*CO + t]      = acca;
        x1[obase + (long long)n*CO + t + 64] = accb;
        sa += acca; qa = fmaf(acca, acca, qa);
        sb += accb; qb = fmaf(accb, accb, qb);
    }
    atomicAdd(&ssum[t],      sa);
    atomicAdd(&ssq[t],       qa);
    atomicAdd(&ssum[t + 64], sb);
    atomicAdd(&ssq[t + 64],  qb);
}

// ---------------------------------------------------------------------------
// Pass 2: read x1, BN1+ReLU -> LDS, x2 = h @ W1^T in place, layer-2 stats.
// 64 threads, TN=2 channels/thread; W1 rows (256 floats) in registers.
// ---------------------------------------------------------------------------
__global__ void __launch_bounds__(64, 1) sa_pass2(
    float* __restrict__ x, const float* __restrict__ w1,
    const float* __restrict__ g0, const float* __restrict__ b0,
    const float* __restrict__ s1sum, const float* __restrict__ s1sq,
    float* __restrict__ s2sum, float* __restrict__ s2sq, float invN, int NS)
{
    __shared__ float hs[32*CO];
    int m = blockIdx.x, t = threadIdx.x;
    int u = t + 64;

    float meana = s1sum[t] * invN;
    float vara  = s1sq[t] * invN - meana * meana;
    float ka    = rsqrtf(vara + 1e-5f) * g0[t];
    float sha   = b0[t] - meana * ka;
    float meanb = s1sum[u] * invN;
    float varb  = s1sq[u] * invN - meanb * meanb;
    float kb    = rsqrtf(varb + 1e-5f) * g0[u];
    float shb   = b0[u] - meanb * kb;

    long long base = (long long)m*NS*CO;
    for (int n = 0; n < NS; n++) {
        float ha = x[base + (long long)n*CO + t] * ka + sha;
        float hb = x[base + (long long)n*CO + u] * kb + shb;
        hs[n*CO + t] = ha > 0.f ? ha : 0.f;
        hs[n*CO + u] = hb > 0.f ? hb : 0.f;
    }
    __syncthreads();

    const float4* wra = (const float4*)(w1 + t*CO);
    const float4* wrb = (const float4*)(w1 + u*CO);
    float4 wa[32], wb[32];
#pragma unroll
    for (int c = 0; c < 32; c++) { wa[c] = wra[c]; wb[c] = wrb[c]; }

    float sa = 0.f, qa = 0.f, sb = 0.f, qb = 0.f;
    for (int n = 0; n < NS; n++) {
        const float4* h4 = (const float4*)(hs + n*CO);
        float a0 = 0.f, a1 = 0.f, c0 = 0.f, c1 = 0.f;
#pragma unroll
        for (int c = 0; c < 32; c += 2) {
            float4 h0 = h4[c], h1 = h4[c+1];
            a0 = fmaf(h0.x, wa[c].x,   a0); a0 = fmaf(h0.y, wa[c].y,   a0);
            a0 = fmaf(h0.z, wa[c].z,   a0); a0 = fmaf(h0.w, wa[c].w,   a0);
            c0 = fmaf(h0.x, wb[c].x,   c0); c0 = fmaf(h0.y, wb[c].y,   c0);
            c0 = fmaf(h0.z, wb[c].z,   c0); c0 = fmaf(h0.w, wb[c].w,   c0);
            a1 = fmaf(h1.x, wa[c+1].x, a1); a1 = fmaf(h1.y, wa[c+1].y, a1);
            a1 = fmaf(h1.z, wa[c+1].z, a1); a1 = fmaf(h1.w, wa[c+1].w, a1);
            c1 = fmaf(h1.x, wb[c+1].x, c1); c1 = fmaf(h1.y, wb[c+1].y, c1);
            c1 = fmaf(h1.z, wb[c+1].z, c1); c1 = fmaf(h1.w, wb[c+1].w, c1);
        }
        float acca = a0 + a1, accb = c0 + c1;
        x[base + (long long)n*CO + t] = acca;
        x[base + (long long)n*CO + u] = accb;
        sa += acca; qa = fmaf(acca, acca, qa);
        sb += accb; qb = fmaf(accb, accb, qb);
    }
    atomicAdd(&s2sum[t], sa);
    atomicAdd(&s2sq[t],  qa);
    atomicAdd(&s2sum[u], sb);
    atomicAdd(&s2sq[u],  qb);
}

// ---------------------------------------------------------------------------
// Pass 3: BN2 + max over samples + ReLU -> f32 output columns.
// ---------------------------------------------------------------------------
__global__ void __launch_bounds__(128, 1) sa_pass3(
    const float* __restrict__ x, const float* __restrict__ g1,
    const float* __restrict__ b1,
    const float* __restrict__ s2sum, const float* __restrict__ s2sq,
    float* __restrict__ outp, float invN, int NS)
{
    int m = blockIdx.x, t = threadIdx.x;
    float mean = s2sum[t] * invN;
    float var  = s2sq[t] * invN - mean * mean;
    float k    = rsqrtf(var + 1e-5f) * g1[t];
    float sh   = b1[t] - mean * k;

    long long base = (long long)m*NS*CO + t;
    float mx = -3.4e38f;
    for (int n = 0; n < NS; n++) {
        float v = x[base + (long long)n*CO] * k + sh;
        mx = v > mx ? v : mx;
    }
    mx = mx > 0.f ? mx : 0.f;
    outp[(long long)m*256 + t] = mx;
}

// ---------------------------------------------------------------------------
extern "C" void kernel_launch(void* const* d_in, const int* in_sizes, int n_in,
                              void* d_out, int out_size, void* d_ws, size_t ws_size,
                              hipStream_t stream)
{
    const float* xyz  = (const float*)d_in[0];
    const float* feat = (const float*)d_in[1];
    const float* nxyz = (const float*)d_in[2];
    const float* w00 = (const float*)d_in[5];
    const float* g00 = (const float*)d_in[6];
    const float* b00 = (const float*)d_in[7];
    const float* w01 = (const float*)d_in[8];
    const float* g01 = (const float*)d_in[9];
    const float* b01 = (const float*)d_in[10];
    const float* w10 = (const float*)d_in[11];
    const float* g10 = (const float*)d_in[12];
    const float* b10 = (const float*)d_in[13];
    const float* w11 = (const float*)d_in[14];
    const float* g11 = (const float*)d_in[15];
    const float* b11 = (const float*)d_in[16];
    float* out = (float*)d_out;

    // ws: stats 4KB | idx0 512KB | idx1 1MB | empty0/1 64KB | x (134 MB f32)
    char*  wsb    = (char*)d_ws;
    float* stats  = (float*)(wsb);
    int*   idx0   = (int*)(wsb + 4096);
    int*   idx1   = (int*)(wsb + 4096 + 524288);
    int*   empty0 = (int*)(wsb + 4096 + 524288 + 1048576);
    int*   empty1 = (int*)(wsb + 4096 + 524288 + 1048576 + 32768);
    float* x      = (float*)(wsb + 4096 + 524288 + 1048576 + 65536);

    StackSAModuleMSG_85761906966880_kernel<<<96, 256, 0, stream>>>(nxyz, out, stats);
    sa_ballq<<<MTOT, 64, 0, stream>>>(xyz, nxyz, idx0, idx1, empty0, empty1);

    float* fout = out + MTOT*3;
    const float invN0 = 1.0f / (float)(MTOT*16);
    const float invN1 = 1.0f / (float)(MTOT*32);

    // scale 0 (r=0.2, ns=16)
    sa_pass1<<<MTOT, 64, 0, stream>>>(xyz, feat, nxyz, idx0, empty0, w00,
                                      x, stats + 0, stats + 128, 16);
    sa_pass2<<<MTOT, 64, 0, stream>>>(x, w01, g00, b00, stats + 0, stats + 128,
                                      stats + 256, stats + 384, invN0, 16);
    sa_pass3<<<MTOT, 128, 0, stream>>>(x, g01, b01, stats + 256, stats + 384,
                                       fout, invN0, 16);
    // scale 1 (r=0.4, ns=32)
    sa_pass1<<<MTOT, 64, 0, stream>>>(xyz, feat, nxyz, idx1, empty1, w10,
                                      x, stats + 512, stats + 640, 32);
    sa_pass2<<<MTOT, 64, 0, stream>>>(x, w11, g10, b10, stats + 512, stats + 640,
                                      stats + 768, stats + 896, invN1, 32);
    sa_pass3<<<MTOT, 128, 0, stream>>>(x, g11, b11, stats + 768, stats + 896,
                                       fout + 128, invN1, 32);

    hipError_t e = hipGetLastError();
    if (e != hipSuccess) EPR("[KL] enqueue err=%d (%s)\n", (int)e, hipGetErrorString(e));
}

// Round 15
// 1129.365 us; speedup vs baseline: 1.3125x; 1.3125x over previous
//
#include <hip/hip_runtime.h>
#include <stdio.h>

#define NBP   8192
#define MTOT  8192
#define CIN   64
#define CO    128

#define EPR(...) do { fprintf(stderr, __VA_ARGS__); fflush(stderr); } while (0)

// ---------------------------------------------------------------------------
// Zero the 1024-float BN-stats region; write output 0 = new_xyz (f32 copy).
// ---------------------------------------------------------------------------
__global__ void __launch_bounds__(256, 1) StackSAModuleMSG_85761906966880_kernel(
    const float* __restrict__ nxyz, float* __restrict__ out, float* __restrict__ stats)
{
    int i = blockIdx.x * 256 + threadIdx.x;
    if (i < 1024) stats[i] = 0.f;
    if (i < MTOT*3) out[i] = nxyz[i];
}

// ---------------------------------------------------------------------------
// Ball query, both scales: one wave per query; f64 d2 (matches np gold).
// ---------------------------------------------------------------------------
__global__ void __launch_bounds__(64, 1) sa_ballq(
    const float* __restrict__ xyz, const float* __restrict__ new_xyz,
    int* __restrict__ idx0, int* __restrict__ idx1,
    int* __restrict__ empty0, int* __restrict__ empty1)
{
    const double r2a = 0.2 * 0.2;
    const double r2b = 0.4 * 0.4;
    int m    = blockIdx.x;
    int lane = threadIdx.x;
    int b    = m >> 11;
    int base = b * NBP;

    double nx = (double)new_xyz[3*m+0];
    double ny = (double)new_xyz[3*m+1];
    double nz = (double)new_xyz[3*m+2];
    double nn = nx*nx + ny*ny + nz*nz;

    int cnt0 = 0, cnt1 = 0;
    int first0 = base, first1 = base;
    unsigned long long lt = (1ull << lane) - 1ull;

    for (int j = 0; j < NBP; j += 64) {
        int gi = base + j + lane;
        double px = (double)xyz[3*gi+0];
        double py = (double)xyz[3*gi+1];
        double pz = (double)xyz[3*gi+2];
        double pp = px*px + py*py + pz*pz;
        double dt = nx*px + ny*py + nz*pz;
        double d2 = nn + pp - 2.0*dt;
        bool in0 = d2 < r2a;
        bool in1 = d2 < r2b;
        unsigned long long m0 = __ballot(in0);
        unsigned long long m1 = __ballot(in1);
        if (in0) {
            int p = cnt0 + __popcll(m0 & lt);
            if (p < 16) idx0[m*16 + p] = gi;
        }
        if (in1) {
            int p = cnt1 + __popcll(m1 & lt);
            if (p < 32) idx1[m*32 + p] = gi;
        }
        if (cnt0 == 0 && m0) first0 = base + j + (__ffsll((long long)m0) - 1);
        if (cnt1 == 0 && m1) first1 = base + j + (__ffsll((long long)m1) - 1);
        cnt0 += __popcll(m0);
        cnt1 += __popcll(m1);
        if (cnt0 >= 16 && cnt1 >= 32) break;
    }
    int c0 = cnt0 < 16 ? cnt0 : 16;
    int c1 = cnt1 < 32 ? cnt1 : 32;
    if (lane >= c0 && lane < 16) idx0[m*16 + lane] = first0;
    if (lane >= c1 && lane < 32) idx1[m*32 + lane] = first1;
    if (lane == 0) { empty0[m] = (cnt0 == 0); empty1[m] = (cnt1 == 0); }
}

// ---------------------------------------------------------------------------
// Pass 1: LDS-tiled GEMM. Block m: gather G (NSx67) and W0 (128x67) into LDS,
// x1 = G @ W0^T, per-channel sum/sumsq. 256 thr = 4 waves; wave wv owns rows
// n = wv*NPW..+NPW-1; lane tx owns cols o = tx and tx+64 (reg tile NPW x 2).
// h-reads broadcast (free); w-reads stride 68 dw == 4 mod 32 (conflict-free).
// ---------------------------------------------------------------------------
template<int NPW>
__global__ void __launch_bounds__(256, 1) sa_pass1(
    const float* __restrict__ xyz, const float* __restrict__ feat,
    const float* __restrict__ nxyz, const int* __restrict__ idx,
    const int* __restrict__ empty, const float* __restrict__ w0,
    float* __restrict__ x1, float* __restrict__ ssum, float* __restrict__ ssq)
{
    const int NS = NPW * 4;
    __shared__ float gs[32*68];
    __shared__ float ws[128*68];
    __shared__ float sred[4*128];
    __shared__ float qred[4*128];
    __shared__ int   lidx[32];
    int m = blockIdx.x, t = threadIdx.x;
    int wv = t >> 6, tx = t & 63;

    if (t < NS) lidx[t] = idx[m*NS + t];
    __syncthreads();
    int emp = empty[m];
    for (int e = t; e < NS*68; e += 256) {
        int n = e / 68, c = e - n*68;
        float v = 0.f;
        if (c < 67 && !emp) {
            int gi = lidx[n];
            v = (c < 3) ? (xyz[3*gi+c] - nxyz[3*m+c])
                        : feat[(long long)gi*CIN + (c-3)];
        }
        gs[e] = v;
    }
    for (int e = t; e < 128*68; e += 256) {
        int o = e / 68, k = e - o*68;
        ws[e] = (k < 67) ? w0[o*67 + k] : 0.f;
    }
    __syncthreads();

    float acc[NPW][2];
#pragma unroll
    for (int i = 0; i < NPW; i++) { acc[i][0] = 0.f; acc[i][1] = 0.f; }
    int o0 = tx, o1 = tx + 64;

    for (int q = 0; q < 17; q++) {
        int k = 4*q;
        float4 wa = *(const float4*)(ws + o0*68 + k);
        float4 wb = *(const float4*)(ws + o1*68 + k);
#pragma unroll
        for (int i = 0; i < NPW; i++) {
            float4 g = *(const float4*)(gs + (wv*NPW + i)*68 + k);
            acc[i][0] = fmaf(g.x, wa.x, acc[i][0]);
            acc[i][0] = fmaf(g.y, wa.y, acc[i][0]);
            acc[i][0] = fmaf(g.z, wa.z, acc[i][0]);
            acc[i][0] = fmaf(g.w, wa.w, acc[i][0]);
            acc[i][1] = fmaf(g.x, wb.x, acc[i][1]);
            acc[i][1] = fmaf(g.y, wb.y, acc[i][1]);
            acc[i][1] = fmaf(g.z, wb.z, acc[i][1]);
            acc[i][1] = fmaf(g.w, wb.w, acc[i][1]);
        }
    }

    long long base = (long long)m*NS*CO;
    float s0 = 0.f, q0 = 0.f, s1 = 0.f, q1 = 0.f;
#pragma unroll
    for (int i = 0; i < NPW; i++) {
        int n = wv*NPW + i;
        float a = acc[i][0], b = acc[i][1];
        x1[base + (long long)n*CO + o0] = a;
        x1[base + (long long)n*CO + o1] = b;
        s0 += a; q0 = fmaf(a, a, q0);
        s1 += b; q1 = fmaf(b, b, q1);
    }
    sred[wv*128 + o0] = s0; sred[wv*128 + o1] = s1;
    qred[wv*128 + o0] = q0; qred[wv*128 + o1] = q1;
    __syncthreads();
    if (wv == 0) {
        float ssa = sred[o0] + sred[128+o0] + sred[256+o0] + sred[384+o0];
        float ssb = sred[o1] + sred[128+o1] + sred[256+o1] + sred[384+o1];
        float qqa = qred[o0] + qred[128+o0] + qred[256+o0] + qred[384+o0];
        float qqb = qred[o1] + qred[128+o1] + qred[256+o1] + qred[384+o1];
        atomicAdd(&ssum[o0], ssa); atomicAdd(&ssq[o0], qqa);
        atomicAdd(&ssum[o1], ssb); atomicAdd(&ssq[o1], qqb);
    }
}

// ---------------------------------------------------------------------------
// Pass 2: LDS-tiled GEMM. Stage h = relu(BN1(x1)) (NSx128) into LDS, W1 in
// two 64-wide k-chunks (128x68-padded LDS each); x2 = h @ W1^T in place;
// layer-2 stats. Same 4-wave / NPWx2 register-tile layout as pass 1.
// ---------------------------------------------------------------------------
template<int NPW>
__global__ void __launch_bounds__(256, 1) sa_pass2(
    float* __restrict__ x, const float* __restrict__ w1,
    const float* __restrict__ g0, const float* __restrict__ b0,
    const float* __restrict__ s1sum, const float* __restrict__ s1sq,
    float* __restrict__ s2sum, float* __restrict__ s2sq, float invN)
{
    const int NS = NPW * 4;
    __shared__ float hs[32*128];
    __shared__ float wsc[128*68];
    __shared__ float kv[128], sv[128];
    __shared__ float sred[4*128];
    __shared__ float qred[4*128];
    int m = blockIdx.x, t = threadIdx.x;
    int wv = t >> 6, tx = t & 63;

    if (t < 128) {
        float mean = s1sum[t] * invN;
        float var  = s1sq[t] * invN - mean * mean;
        float k    = rsqrtf(var + 1e-5f) * g0[t];
        kv[t] = k;
        sv[t] = b0[t] - mean * k;
    }
    __syncthreads();

    long long base = (long long)m*NS*CO;
    for (int e = t; e < NS*32; e += 256) {      // float4 units
        int n = e >> 5, c4 = e & 31;
        float4 v  = *(const float4*)(x + base + (long long)n*CO + 4*c4);
        float4 kk = *(const float4*)(kv + 4*c4);
        float4 ss = *(const float4*)(sv + 4*c4);
        v.x = fmaxf(fmaf(v.x, kk.x, ss.x), 0.f);
        v.y = fmaxf(fmaf(v.y, kk.y, ss.y), 0.f);
        v.z = fmaxf(fmaf(v.z, kk.z, ss.z), 0.f);
        v.w = fmaxf(fmaf(v.w, kk.w, ss.w), 0.f);
        *(float4*)(hs + n*128 + 4*c4) = v;
    }

    float acc[NPW][2];
#pragma unroll
    for (int i = 0; i < NPW; i++) { acc[i][0] = 0.f; acc[i][1] = 0.f; }
    int o0 = tx, o1 = tx + 64;

    for (int ch = 0; ch < 2; ch++) {
        __syncthreads();   // hs ready (ch0) / previous chunk consumed (ch1)
        for (int e = t; e < 128*16; e += 256) { // float4 units
            int o = e >> 4, k4 = e & 15;
            float4 v = *(const float4*)(w1 + o*CO + ch*64 + 4*k4);
            *(float4*)(wsc + o*68 + 4*k4) = v;
        }
        __syncthreads();
        for (int q = 0; q < 16; q++) {
            int k  = 4*q;
            int kh = ch*64 + k;
            float4 wa = *(const float4*)(wsc + o0*68 + k);
            float4 wb = *(const float4*)(wsc + o1*68 + k);
#pragma unroll
            for (int i = 0; i < NPW; i++) {
                float4 h = *(const float4*)(hs + (wv*NPW + i)*128 + kh);
                acc[i][0] = fmaf(h.x, wa.x, acc[i][0]);
                acc[i][0] = fmaf(h.y, wa.y, acc[i][0]);
                acc[i][0] = fmaf(h.z, wa.z, acc[i][0]);
                acc[i][0] = fmaf(h.w, wa.w, acc[i][0]);
                acc[i][1] = fmaf(h.x, wb.x, acc[i][1]);
                acc[i][1] = fmaf(h.y, wb.y, acc[i][1]);
                acc[i][1] = fmaf(h.z, wb.z, acc[i][1]);
                acc[i][1] = fmaf(h.w, wb.w, acc[i][1]);
            }
        }
    }

    float s0 = 0.f, q0 = 0.f, s1 = 0.f, q1 = 0.f;
#pragma unroll
    for (int i = 0; i < NPW; i++) {
        int n = wv*NPW + i;
        float a = acc[i][0], b = acc[i][1];
        x[base + (long long)n*CO + o0] = a;
        x[base + (long long)n*CO + o1] = b;
        s0 += a; q0 = fmaf(a, a, q0);
        s1 += b; q1 = fmaf(b, b, q1);
    }
    sred[wv*128 + o0] = s0; sred[wv*128 + o1] = s1;
    qred[wv*128 + o0] = q0; qred[wv*128 + o1] = q1;
    __syncthreads();
    if (wv == 0) {
        float ssa = sred[o0] + sred[128+o0] + sred[256+o0] + sred[384+o0];
        float ssb = sred[o1] + sred[128+o1] + sred[256+o1] + sred[384+o1];
        float qqa = qred[o0] + qred[128+o0] + qred[256+o0] + qred[384+o0];
        float qqb = qred[o1] + qred[128+o1] + qred[256+o1] + qred[384+o1];
        atomicAdd(&s2sum[o0], ssa); atomicAdd(&s2sq[o0], qqa);
        atomicAdd(&s2sum[o1], ssb); atomicAdd(&s2sq[o1], qqb);
    }
}

// ---------------------------------------------------------------------------
// Pass 3: BN2 + max over samples + ReLU -> f32 output columns.
// ---------------------------------------------------------------------------
__global__ void __launch_bounds__(128, 1) sa_pass3(
    const float* __restrict__ x, const float* __restrict__ g1,
    const float* __restrict__ b1,
    const float* __restrict__ s2sum, const float* __restrict__ s2sq,
    float* __restrict__ outp, float invN, int NS)
{
    int m = blockIdx.x, t = threadIdx.x;
    float mean = s2sum[t] * invN;
    float var  = s2sq[t] * invN - mean * mean;
    float k    = rsqrtf(var + 1e-5f) * g1[t];
    float sh   = b1[t] - mean * k;

    long long base = (long long)m*NS*CO + t;
    float mx = -3.4e38f;
    for (int n = 0; n < NS; n++) {
        float v = x[base + (long long)n*CO] * k + sh;
        mx = v > mx ? v : mx;
    }
    mx = mx > 0.f ? mx : 0.f;
    outp[(long long)m*256 + t] = mx;
}

// ---------------------------------------------------------------------------
extern "C" void kernel_launch(void* const* d_in, const int* in_sizes, int n_in,
                              void* d_out, int out_size, void* d_ws, size_t ws_size,
                              hipStream_t stream)
{
    const float* xyz  = (const float*)d_in[0];
    const float* feat = (const float*)d_in[1];
    const float* nxyz = (const float*)d_in[2];
    const float* w00 = (const float*)d_in[5];
    const float* g00 = (const float*)d_in[6];
    const float* b00 = (const float*)d_in[7];
    const float* w01 = (const float*)d_in[8];
    const float* g01 = (const float*)d_in[9];
    const float* b01 = (const float*)d_in[10];
    const float* w10 = (const float*)d_in[11];
    const float* g10 = (const float*)d_in[12];
    const float* b10 = (const float*)d_in[13];
    const float* w11 = (const float*)d_in[14];
    const float* g11 = (const float*)d_in[15];
    const float* b11 = (const float*)d_in[16];
    float* out = (float*)d_out;

    // ws: stats 4KB | idx0 512KB | idx1 1MB | empty0/1 64KB | x (134 MB f32)
    char*  wsb    = (char*)d_ws;
    float* stats  = (float*)(wsb);
    int*   idx0   = (int*)(wsb + 4096);
    int*   idx1   = (int*)(wsb + 4096 + 524288);
    int*   empty0 = (int*)(wsb + 4096 + 524288 + 1048576);
    int*   empty1 = (int*)(wsb + 4096 + 524288 + 1048576 + 32768);
    float* x      = (float*)(wsb + 4096 + 524288 + 1048576 + 65536);

    StackSAModuleMSG_85761906966880_kernel<<<96, 256, 0, stream>>>(nxyz, out, stats);
    sa_ballq<<<MTOT, 64, 0, stream>>>(xyz, nxyz, idx0, idx1, empty0, empty1);

    float* fout = out + MTOT*3;
    const float invN0 = 1.0f / (float)(MTOT*16);
    const float invN1 = 1.0f / (float)(MTOT*32);

    // scale 0 (r=0.2, ns=16)
    sa_pass1<4><<<MTOT, 256, 0, stream>>>(xyz, feat, nxyz, idx0, empty0, w00,
                                          x, stats + 0, stats + 128);
    sa_pass2<4><<<MTOT, 256, 0, stream>>>(x, w01, g00, b00, stats + 0, stats + 128,
                                          stats + 256, stats + 384, invN0);
    sa_pass3<<<MTOT, 128, 0, stream>>>(x, g01, b01, stats + 256, stats + 384,
                                       fout, invN0, 16);
    // scale 1 (r=0.4, ns=32)
    sa_pass1<8><<<MTOT, 256, 0, stream>>>(xyz, feat, nxyz, idx1, empty1, w10,
                                          x, stats + 512, stats + 640);
    sa_pass2<8><<<MTOT, 256, 0, stream>>>(x, w11, g10, b10, stats + 512, stats + 640,
                                          stats + 768, stats + 896, invN1);
    sa_pass3<<<MTOT, 128, 0, stream>>>(x, g11, b11, stats + 768, stats + 896,
                                       fout + 128, invN1, 32);

    hipError_t e = hipGetLastError();
    if (e != hipSuccess) EPR("[KL] enqueue err=%d (%s)\n", (int)e, hipGetErrorString(e));
}

// Round 16
// 1056.306 us; speedup vs baseline: 1.4033x; 1.0692x over previous
//
#include <hip/hip_runtime.h>
#include <stdio.h>

#define NBP   8192
#define MTOT  8192
#define CIN   64
#define CO    128

#define EPR(...) do { fprintf(stderr, __VA_ARGS__); fflush(stderr); } while (0)

// ---------------------------------------------------------------------------
// Zero the 1024-float BN-stats region; write output 0 = new_xyz (f32 copy).
// ---------------------------------------------------------------------------
__global__ void __launch_bounds__(256, 1) StackSAModuleMSG_85761906966880_kernel(
    const float* __restrict__ nxyz, float* __restrict__ out, float* __restrict__ stats)
{
    int i = blockIdx.x * 256 + threadIdx.x;
    if (i < 1024) stats[i] = 0.f;
    if (i < MTOT*3) out[i] = nxyz[i];
}

// ---------------------------------------------------------------------------
// Ball query, both scales: one wave per query; f64 d2 (matches np gold).
// ---------------------------------------------------------------------------
__global__ void __launch_bounds__(64, 1) sa_ballq(
    const float* __restrict__ xyz, const float* __restrict__ new_xyz,
    int* __restrict__ idx0, int* __restrict__ idx1,
    int* __restrict__ empty0, int* __restrict__ empty1)
{
    const double r2a = 0.2 * 0.2;
    const double r2b = 0.4 * 0.4;
    int m    = blockIdx.x;
    int lane = threadIdx.x;
    int b    = m >> 11;
    int base = b * NBP;

    double nx = (double)new_xyz[3*m+0];
    double ny = (double)new_xyz[3*m+1];
    double nz = (double)new_xyz[3*m+2];
    double nn = nx*nx + ny*ny + nz*nz;

    int cnt0 = 0, cnt1 = 0;
    int first0 = base, first1 = base;
    unsigned long long lt = (1ull << lane) - 1ull;

    for (int j = 0; j < NBP; j += 64) {
        int gi = base + j + lane;
        double px = (double)xyz[3*gi+0];
        double py = (double)xyz[3*gi+1];
        double pz = (double)xyz[3*gi+2];
        double pp = px*px + py*py + pz*pz;
        double dt = nx*px + ny*py + nz*pz;
        double d2 = nn + pp - 2.0*dt;
        bool in0 = d2 < r2a;
        bool in1 = d2 < r2b;
        unsigned long long m0 = __ballot(in0);
        unsigned long long m1 = __ballot(in1);
        if (in0) {
            int p = cnt0 + __popcll(m0 & lt);
            if (p < 16) idx0[m*16 + p] = gi;
        }
        if (in1) {
            int p = cnt1 + __popcll(m1 & lt);
            if (p < 32) idx1[m*32 + p] = gi;
        }
        if (cnt0 == 0 && m0) first0 = base + j + (__ffsll((long long)m0) - 1);
        if (cnt1 == 0 && m1) first1 = base + j + (__ffsll((long long)m1) - 1);
        cnt0 += __popcll(m0);
        cnt1 += __popcll(m1);
        if (cnt0 >= 16 && cnt1 >= 32) break;
    }
    int c0 = cnt0 < 16 ? cnt0 : 16;
    int c1 = cnt1 < 32 ? cnt1 : 32;
    if (lane >= c0 && lane < 16) idx0[m*16 + lane] = first0;
    if (lane >= c1 && lane < 32) idx1[m*32 + lane] = first1;
    if (lane == 0) { empty0[m] = (cnt0 == 0); empty1[m] = (cnt1 == 0); }
}

// ---------------------------------------------------------------------------
// Pass 1: LDS-tiled GEMM, 512 threads = 8 waves. Wave wv owns rows
// n = wv*NPW..+NPW-1 (NPW = NS/8); lane tx owns cols tx and tx+64.
// G (NSx67) and W0 (128x67) staged in LDS (row stride 68: 68%32==4, the
// strided w-reads spread over all banks; g-reads are wave-broadcast).
// ---------------------------------------------------------------------------
template<int NPW>
__global__ void __launch_bounds__(512, 6) sa_pass1(
    const float* __restrict__ xyz, const float* __restrict__ feat,
    const float* __restrict__ nxyz, const int* __restrict__ idx,
    const int* __restrict__ empty, const float* __restrict__ w0,
    float* __restrict__ x1, float* __restrict__ ssum, float* __restrict__ ssq)
{
    const int NS = NPW * 8;
    __shared__ float gs[32*68];
    __shared__ float ws[128*68];
    __shared__ float sred[8*128];
    __shared__ float qred[8*128];
    __shared__ int   lidx[32];
    int m = blockIdx.x, t = threadIdx.x;
    int wv = t >> 6, tx = t & 63;

    if (t < NS) lidx[t] = idx[m*NS + t];
    __syncthreads();
    int emp = empty[m];
    for (int e = t; e < NS*68; e += 512) {
        int n = e / 68, c = e - n*68;
        float v = 0.f;
        if (c < 67 && !emp) {
            int gi = lidx[n];
            v = (c < 3) ? (xyz[3*gi+c] - nxyz[3*m+c])
                        : feat[(long long)gi*CIN + (c-3)];
        }
        gs[e] = v;
    }
    for (int e = t; e < 128*68; e += 512) {
        int o = e / 68, k = e - o*68;
        ws[e] = (k < 67) ? w0[o*67 + k] : 0.f;
    }
    __syncthreads();

    float acc[NPW][2];
#pragma unroll
    for (int i = 0; i < NPW; i++) { acc[i][0] = 0.f; acc[i][1] = 0.f; }
    int o0 = tx, o1 = tx + 64;

#pragma unroll
    for (int q = 0; q < 17; q++) {
        int k = 4*q;
        float4 wa = *(const float4*)(ws + o0*68 + k);
        float4 wb = *(const float4*)(ws + o1*68 + k);
#pragma unroll
        for (int i = 0; i < NPW; i++) {
            float4 g = *(const float4*)(gs + (wv*NPW + i)*68 + k);
            acc[i][0] = fmaf(g.x, wa.x, acc[i][0]);
            acc[i][0] = fmaf(g.y, wa.y, acc[i][0]);
            acc[i][0] = fmaf(g.z, wa.z, acc[i][0]);
            acc[i][0] = fmaf(g.w, wa.w, acc[i][0]);
            acc[i][1] = fmaf(g.x, wb.x, acc[i][1]);
            acc[i][1] = fmaf(g.y, wb.y, acc[i][1]);
            acc[i][1] = fmaf(g.z, wb.z, acc[i][1]);
            acc[i][1] = fmaf(g.w, wb.w, acc[i][1]);
        }
    }

    long long base = (long long)m*NS*CO;
    float s0 = 0.f, q0 = 0.f, s1 = 0.f, q1 = 0.f;
#pragma unroll
    for (int i = 0; i < NPW; i++) {
        int n = wv*NPW + i;
        float a = acc[i][0], b = acc[i][1];
        x1[base + (long long)n*CO + o0] = a;
        x1[base + (long long)n*CO + o1] = b;
        s0 += a; q0 = fmaf(a, a, q0);
        s1 += b; q1 = fmaf(b, b, q1);
    }
    sred[wv*128 + o0] = s0; sred[wv*128 + o1] = s1;
    qred[wv*128 + o0] = q0; qred[wv*128 + o1] = q1;
    __syncthreads();
    if (wv == 0) {
        float ssa = 0.f, ssb = 0.f, qqa = 0.f, qqb = 0.f;
#pragma unroll
        for (int r = 0; r < 8; r++) {
            ssa += sred[r*128 + o0]; ssb += sred[r*128 + o1];
            qqa += qred[r*128 + o0]; qqb += qred[r*128 + o1];
        }
        atomicAdd(&ssum[o0], ssa); atomicAdd(&ssq[o0], qqa);
        atomicAdd(&ssum[o1], ssb); atomicAdd(&ssq[o1], qqb);
    }
}

// ---------------------------------------------------------------------------
// Pass 2: LDS-tiled GEMM, 512 threads = 8 waves. Stage h = relu(BN1(x1))
// (NSx128) into LDS; W1 in two 64-wide k-chunks; x2 = h @ W1^T in place;
// layer-2 stats. Wave wv owns NPW = NS/8 rows; lane owns cols tx, tx+64.
// ---------------------------------------------------------------------------
template<int NPW>
__global__ void __launch_bounds__(512, 4) sa_pass2(
    float* __restrict__ x, const float* __restrict__ w1,
    const float* __restrict__ g0, const float* __restrict__ b0,
    const float* __restrict__ s1sum, const float* __restrict__ s1sq,
    float* __restrict__ s2sum, float* __restrict__ s2sq, float invN)
{
    const int NS = NPW * 8;
    __shared__ float hs[32*128];
    __shared__ float wsc[128*68];
    __shared__ float kv[128], sv[128];
    __shared__ float sred[8*128];
    __shared__ float qred[8*128];
    int m = blockIdx.x, t = threadIdx.x;
    int wv = t >> 6, tx = t & 63;

    if (t < 128) {
        float mean = s1sum[t] * invN;
        float var  = s1sq[t] * invN - mean * mean;
        float k    = rsqrtf(var + 1e-5f) * g0[t];
        kv[t] = k;
        sv[t] = b0[t] - mean * k;
    }
    __syncthreads();

    long long base = (long long)m*NS*CO;
    for (int e = t; e < NS*32; e += 512) {      // float4 units
        int n = e >> 5, c4 = e & 31;
        float4 v  = *(const float4*)(x + base + (long long)n*CO + 4*c4);
        float4 kk = *(const float4*)(kv + 4*c4);
        float4 ss = *(const float4*)(sv + 4*c4);
        v.x = fmaxf(fmaf(v.x, kk.x, ss.x), 0.f);
        v.y = fmaxf(fmaf(v.y, kk.y, ss.y), 0.f);
        v.z = fmaxf(fmaf(v.z, kk.z, ss.z), 0.f);
        v.w = fmaxf(fmaf(v.w, kk.w, ss.w), 0.f);
        *(float4*)(hs + n*128 + 4*c4) = v;
    }

    float acc[NPW][2];
#pragma unroll
    for (int i = 0; i < NPW; i++) { acc[i][0] = 0.f; acc[i][1] = 0.f; }
    int o0 = tx, o1 = tx + 64;

    for (int ch = 0; ch < 2; ch++) {
        __syncthreads();   // hs ready (ch0) / previous chunk consumed (ch1)
        for (int e = t; e < 128*16; e += 512) { // float4 units
            int o = e >> 4, k4 = e & 15;
            float4 v = *(const float4*)(w1 + o*CO + ch*64 + 4*k4);
            *(float4*)(wsc + o*68 + 4*k4) = v;
        }
        __syncthreads();
#pragma unroll
        for (int q = 0; q < 16; q++) {
            int k  = 4*q;
            int kh = ch*64 + k;
            float4 wa = *(const float4*)(wsc + o0*68 + k);
            float4 wb = *(const float4*)(wsc + o1*68 + k);
#pragma unroll
            for (int i = 0; i < NPW; i++) {
                float4 h = *(const float4*)(hs + (wv*NPW + i)*128 + kh);
                acc[i][0] = fmaf(h.x, wa.x, acc[i][0]);
                acc[i][0] = fmaf(h.y, wa.y, acc[i][0]);
                acc[i][0] = fmaf(h.z, wa.z, acc[i][0]);
                acc[i][0] = fmaf(h.w, wa.w, acc[i][0]);
                acc[i][1] = fmaf(h.x, wb.x, acc[i][1]);
                acc[i][1] = fmaf(h.y, wb.y, acc[i][1]);
                acc[i][1] = fmaf(h.z, wb.z, acc[i][1]);
                acc[i][1] = fmaf(h.w, wb.w, acc[i][1]);
            }
        }
    }

    float s0 = 0.f, q0 = 0.f, s1 = 0.f, q1 = 0.f;
#pragma unroll
    for (int i = 0; i < NPW; i++) {
        int n = wv*NPW + i;
        float a = acc[i][0], b = acc[i][1];
        x[base + (long long)n*CO + o0] = a;
        x[base + (long long)n*CO + o1] = b;
        s0 += a; q0 = fmaf(a, a, q0);
        s1 += b; q1 = fmaf(b, b, q1);
    }
    sred[wv*128 + o0] = s0; sred[wv*128 + o1] = s1;
    qred[wv*128 + o0] = q0; qred[wv*128 + o1] = q1;
    __syncthreads();
    if (wv == 0) {
        float ssa = 0.f, ssb = 0.f, qqa = 0.f, qqb = 0.f;
#pragma unroll
        for (int r = 0; r < 8; r++) {
            ssa += sred[r*128 + o0]; ssb += sred[r*128 + o1];
            qqa += qred[r*128 + o0]; qqb += qred[r*128 + o1];
        }
        atomicAdd(&s2sum[o0], ssa); atomicAdd(&s2sq[o0], qqa);
        atomicAdd(&s2sum[o1], ssb); atomicAdd(&s2sq[o1], qqb);
    }
}

// ---------------------------------------------------------------------------
// Pass 3: BN2 + max over samples + ReLU -> f32 output columns.
// ---------------------------------------------------------------------------
__global__ void __launch_bounds__(128, 1) sa_pass3(
    const float* __restrict__ x, const float* __restrict__ g1,
    const float* __restrict__ b1,
    const float* __restrict__ s2sum, const float* __restrict__ s2sq,
    float* __restrict__ outp, float invN, int NS)
{
    int m = blockIdx.x, t = threadIdx.x;
    float mean = s2sum[t] * invN;
    float var  = s2sq[t] * invN - mean * mean;
    float k    = rsqrtf(var + 1e-5f) * g1[t];
    float sh   = b1[t] - mean * k;

    long long base = (long long)m*NS*CO + t;
    float mx = -3.4e38f;
    for (int n = 0; n < NS; n++) {
        float v = x[base + (long long)n*CO] * k + sh;
        mx = v > mx ? v : mx;
    }
    mx = mx > 0.f ? mx : 0.f;
    outp[(long long)m*256 + t] = mx;
}

// ---------------------------------------------------------------------------
extern "C" void kernel_launch(void* const* d_in, const int* in_sizes, int n_in,
                              void* d_out, int out_size, void* d_ws, size_t ws_size,
                              hipStream_t stream)
{
    const float* xyz  = (const float*)d_in[0];
    const float* feat = (const float*)d_in[1];
    const float* nxyz = (const float*)d_in[2];
    const float* w00 = (const float*)d_in[5];
    const float* g00 = (const float*)d_in[6];
    const float* b00 = (const float*)d_in[7];
    const float* w01 = (const float*)d_in[8];
    const float* g01 = (const float*)d_in[9];
    const float* b01 = (const float*)d_in[10];
    const float* w10 = (const float*)d_in[11];
    const float* g10 = (const float*)d_in[12];
    const float* b10 = (const float*)d_in[13];
    const float* w11 = (const float*)d_in[14];
    const float* g11 = (const float*)d_in[15];
    const float* b11 = (const float*)d_in[16];
    float* out = (float*)d_out;

    // ws: stats 4KB | idx0 512KB | idx1 1MB | empty0/1 64KB | x (134 MB f32)
    char*  wsb    = (char*)d_ws;
    float* stats  = (float*)(wsb);
    int*   idx0   = (int*)(wsb + 4096);
    int*   idx1   = (int*)(wsb + 4096 + 524288);
    int*   empty0 = (int*)(wsb + 4096 + 524288 + 1048576);
    int*   empty1 = (int*)(wsb + 4096 + 524288 + 1048576 + 32768);
    float* x      = (float*)(wsb + 4096 + 524288 + 1048576 + 65536);

    StackSAModuleMSG_85761906966880_kernel<<<96, 256, 0, stream>>>(nxyz, out, stats);
    sa_ballq<<<MTOT, 64, 0, stream>>>(xyz, nxyz, idx0, idx1, empty0, empty1);

    float* fout = out + MTOT*3;
    const float invN0 = 1.0f / (float)(MTOT*16);
    const float invN1 = 1.0f / (float)(MTOT*32);

    // scale 0 (r=0.2, ns=16)  -> NPW = 16/8 = 2
    sa_pass1<2><<<MTOT, 512, 0, stream>>>(xyz, feat, nxyz, idx0, empty0, w00,
                                          x, stats + 0, stats + 128);
    sa_pass2<2><<<MTOT, 512, 0, stream>>>(x, w01, g00, b00, stats + 0, stats + 128,
                                          stats + 256, stats + 384, invN0);
    sa_pass3<<<MTOT, 128, 0, stream>>>(x, g01, b01, stats + 256, stats + 384,
                                       fout, invN0, 16);
    // scale 1 (r=0.4, ns=32)  -> NPW = 32/8 = 4
    sa_pass1<4><<<MTOT, 512, 0, stream>>>(xyz, feat, nxyz, idx1, empty1, w10,
                                          x, stats + 512, stats + 640);
    sa_pass2<4><<<MTOT, 512, 0, stream>>>(x, w11, g10, b10, stats + 512, stats + 640,
                                          stats + 768, stats + 896, invN1);
    sa_pass3<<<MTOT, 128, 0, stream>>>(x, g11, b11, stats + 768, stats + 896,
                                       fout + 128, invN1, 32);

    hipError_t e = hipGetLastError();
    if (e != hipSuccess) EPR("[KL] enqueue err=%d (%s)\n", (int)e, hipGetErrorString(e));
}

// Round 17
// 1024.335 us; speedup vs baseline: 1.4471x; 1.0312x over previous
//
#include <hip/hip_runtime.h>
#include <stdio.h>

#define NBP   8192
#define MTOT  8192
#define CIN   64
#define CO    128

#define EPR(...) do { fprintf(stderr, __VA_ARGS__); fflush(stderr); } while (0)

// ---------------------------------------------------------------------------
// Zero the 1024-float BN-stats region; write output 0 = new_xyz (f32 copy).
// ---------------------------------------------------------------------------
__global__ void __launch_bounds__(256, 1) StackSAModuleMSG_85761906966880_kernel(
    const float* __restrict__ nxyz, float* __restrict__ out, float* __restrict__ stats)
{
    int i = blockIdx.x * 256 + threadIdx.x;
    if (i < 1024) stats[i] = 0.f;
    if (i < MTOT*3) out[i] = nxyz[i];
}

// ---------------------------------------------------------------------------
// Ball query, both scales: one wave per query; f64 d2 (matches np gold).
// ---------------------------------------------------------------------------
__global__ void __launch_bounds__(64, 1) sa_ballq(
    const float* __restrict__ xyz, const float* __restrict__ new_xyz,
    int* __restrict__ idx0, int* __restrict__ idx1,
    int* __restrict__ empty0, int* __restrict__ empty1)
{
    const double r2a = 0.2 * 0.2;
    const double r2b = 0.4 * 0.4;
    int m    = blockIdx.x;
    int lane = threadIdx.x;
    int b    = m >> 11;
    int base = b * NBP;

    double nx = (double)new_xyz[3*m+0];
    double ny = (double)new_xyz[3*m+1];
    double nz = (double)new_xyz[3*m+2];
    double nn = nx*nx + ny*ny + nz*nz;

    int cnt0 = 0, cnt1 = 0;
    int first0 = base, first1 = base;
    unsigned long long lt = (1ull << lane) - 1ull;

    for (int j = 0; j < NBP; j += 64) {
        int gi = base + j + lane;
        double px = (double)xyz[3*gi+0];
        double py = (double)xyz[3*gi+1];
        double pz = (double)xyz[3*gi+2];
        double pp = px*px + py*py + pz*pz;
        double dt = nx*px + ny*py + nz*pz;
        double d2 = nn + pp - 2.0*dt;
        bool in0 = d2 < r2a;
        bool in1 = d2 < r2b;
        unsigned long long m0 = __ballot(in0);
        unsigned long long m1 = __ballot(in1);
        if (in0) {
            int p = cnt0 + __popcll(m0 & lt);
            if (p < 16) idx0[m*16 + p] = gi;
        }
        if (in1) {
            int p = cnt1 + __popcll(m1 & lt);
            if (p < 32) idx1[m*32 + p] = gi;
        }
        if (cnt0 == 0 && m0) first0 = base + j + (__ffsll((long long)m0) - 1);
        if (cnt1 == 0 && m1) first1 = base + j + (__ffsll((long long)m1) - 1);
        cnt0 += __popcll(m0);
        cnt1 += __popcll(m1);
        if (cnt0 >= 16 && cnt1 >= 32) break;
    }
    int c0 = cnt0 < 16 ? cnt0 : 16;
    int c1 = cnt1 < 32 ? cnt1 : 32;
    if (lane >= c0 && lane < 16) idx0[m*16 + lane] = first0;
    if (lane >= c1 && lane < 32) idx1[m*32 + lane] = first1;
    if (lane == 0) { empty0[m] = (cnt0 == 0); empty1[m] = (cnt1 == 0); }
}

// ---------------------------------------------------------------------------
// Pass 1: LDS-tiled GEMM, 512 threads = 8 waves; x1 = G @ W0^T + stats1.
// ---------------------------------------------------------------------------
template<int NPW>
__global__ void __launch_bounds__(512, 6) sa_pass1(
    const float* __restrict__ xyz, const float* __restrict__ feat,
    const float* __restrict__ nxyz, const int* __restrict__ idx,
    const int* __restrict__ empty, const float* __restrict__ w0,
    float* __restrict__ x1, float* __restrict__ ssum, float* __restrict__ ssq)
{
    const int NS = NPW * 8;
    __shared__ float gs[32*68];
    __shared__ float ws[128*68];
    __shared__ float sred[8*128];
    __shared__ float qred[8*128];
    __shared__ int   lidx[32];
    int m = blockIdx.x, t = threadIdx.x;
    int wv = t >> 6, tx = t & 63;

    if (t < NS) lidx[t] = idx[m*NS + t];
    __syncthreads();
    int emp = empty[m];
    for (int e = t; e < NS*68; e += 512) {
        int n = e / 68, c = e - n*68;
        float v = 0.f;
        if (c < 67 && !emp) {
            int gi = lidx[n];
            v = (c < 3) ? (xyz[3*gi+c] - nxyz[3*m+c])
                        : feat[(long long)gi*CIN + (c-3)];
        }
        gs[e] = v;
    }
    for (int e = t; e < 128*68; e += 512) {
        int o = e / 68, k = e - o*68;
        ws[e] = (k < 67) ? w0[o*67 + k] : 0.f;
    }
    __syncthreads();

    float acc[NPW][2];
#pragma unroll
    for (int i = 0; i < NPW; i++) { acc[i][0] = 0.f; acc[i][1] = 0.f; }
    int o0 = tx, o1 = tx + 64;

    for (int q = 0; q < 17; q++) {
        int k = 4*q;
        float4 wa = *(const float4*)(ws + o0*68 + k);
        float4 wb = *(const float4*)(ws + o1*68 + k);
#pragma unroll
        for (int i = 0; i < NPW; i++) {
            float4 g = *(const float4*)(gs + (wv*NPW + i)*68 + k);
            acc[i][0] = fmaf(g.x, wa.x, acc[i][0]);
            acc[i][0] = fmaf(g.y, wa.y, acc[i][0]);
            acc[i][0] = fmaf(g.z, wa.z, acc[i][0]);
            acc[i][0] = fmaf(g.w, wa.w, acc[i][0]);
            acc[i][1] = fmaf(g.x, wb.x, acc[i][1]);
            acc[i][1] = fmaf(g.y, wb.y, acc[i][1]);
            acc[i][1] = fmaf(g.z, wb.z, acc[i][1]);
            acc[i][1] = fmaf(g.w, wb.w, acc[i][1]);
        }
    }

    long long base = (long long)m*NS*CO;
    float s0 = 0.f, q0 = 0.f, s1 = 0.f, q1 = 0.f;
#pragma unroll
    for (int i = 0; i < NPW; i++) {
        int n = wv*NPW + i;
        float a = acc[i][0], b = acc[i][1];
        x1[base + (long long)n*CO + o0] = a;
        x1[base + (long long)n*CO + o1] = b;
        s0 += a; q0 = fmaf(a, a, q0);
        s1 += b; q1 = fmaf(b, b, q1);
    }
    sred[wv*128 + o0] = s0; sred[wv*128 + o1] = s1;
    qred[wv*128 + o0] = q0; qred[wv*128 + o1] = q1;
    __syncthreads();
    if (wv == 0) {
        float ssa = 0.f, ssb = 0.f, qqa = 0.f, qqb = 0.f;
#pragma unroll
        for (int r = 0; r < 8; r++) {
            ssa += sred[r*128 + o0]; ssb += sred[r*128 + o1];
            qqa += qred[r*128 + o0]; qqb += qred[r*128 + o1];
        }
        atomicAdd(&ssum[o0], ssa); atomicAdd(&ssq[o0], qqa);
        atomicAdd(&ssum[o1], ssb); atomicAdd(&ssq[o1], qqb);
    }
}

// ---------------------------------------------------------------------------
// Pass 2: LDS-tiled GEMM. h = relu(BN1(x1)) -> LDS; x2 = h @ W1^T kept in
// registers only: emits per-(m,o) max & min of x2 plus layer-2 stats.
// (max/min commute bit-exactly with the monotone affine BN2 in pass 3.)
// ---------------------------------------------------------------------------
template<int NPW>
__global__ void __launch_bounds__(512, 4) sa_pass2(
    const float* __restrict__ x1, const float* __restrict__ w1,
    const float* __restrict__ g0, const float* __restrict__ b0,
    const float* __restrict__ s1sum, const float* __restrict__ s1sq,
    float* __restrict__ s2sum, float* __restrict__ s2sq,
    float* __restrict__ mxo, float* __restrict__ mno, float invN)
{
    const int NS = NPW * 8;
    __shared__ float hs[32*128];
    __shared__ float wsc[128*68];
    __shared__ float kv[128], sv[128];
    __shared__ float sred[8*128];
    __shared__ float qred[8*128];
    int m = blockIdx.x, t = threadIdx.x;
    int wv = t >> 6, tx = t & 63;

    if (t < 128) {
        float mean = s1sum[t] * invN;
        float var  = s1sq[t] * invN - mean * mean;
        float k    = rsqrtf(var + 1e-5f) * g0[t];
        kv[t] = k;
        sv[t] = b0[t] - mean * k;
    }
    __syncthreads();

    long long base = (long long)m*NS*CO;
    for (int e = t; e < NS*32; e += 512) {      // float4 units
        int n = e >> 5, c4 = e & 31;
        float4 v  = *(const float4*)(x1 + base + (long long)n*CO + 4*c4);
        float4 kk = *(const float4*)(kv + 4*c4);
        float4 ss = *(const float4*)(sv + 4*c4);
        v.x = fmaxf(fmaf(v.x, kk.x, ss.x), 0.f);
        v.y = fmaxf(fmaf(v.y, kk.y, ss.y), 0.f);
        v.z = fmaxf(fmaf(v.z, kk.z, ss.z), 0.f);
        v.w = fmaxf(fmaf(v.w, kk.w, ss.w), 0.f);
        *(float4*)(hs + n*128 + 4*c4) = v;
    }

    float acc[NPW][2];
#pragma unroll
    for (int i = 0; i < NPW; i++) { acc[i][0] = 0.f; acc[i][1] = 0.f; }
    int o0 = tx, o1 = tx + 64;

    for (int ch = 0; ch < 2; ch++) {
        __syncthreads();   // hs ready (ch0) / previous chunk consumed (ch1)
        for (int e = t; e < 128*16; e += 512) { // float4 units
            int o = e >> 4, k4 = e & 15;
            float4 v = *(const float4*)(w1 + o*CO + ch*64 + 4*k4);
            *(float4*)(wsc + o*68 + 4*k4) = v;
        }
        __syncthreads();
        for (int q = 0; q < 16; q++) {
            int k  = 4*q;
            int kh = ch*64 + k;
            float4 wa = *(const float4*)(wsc + o0*68 + k);
            float4 wb = *(const float4*)(wsc + o1*68 + k);
#pragma unroll
            for (int i = 0; i < NPW; i++) {
                float4 h = *(const float4*)(hs + (wv*NPW + i)*128 + kh);
                acc[i][0] = fmaf(h.x, wa.x, acc[i][0]);
                acc[i][0] = fmaf(h.y, wa.y, acc[i][0]);
                acc[i][0] = fmaf(h.z, wa.z, acc[i][0]);
                acc[i][0] = fmaf(h.w, wa.w, acc[i][0]);
                acc[i][1] = fmaf(h.x, wb.x, acc[i][1]);
                acc[i][1] = fmaf(h.y, wb.y, acc[i][1]);
                acc[i][1] = fmaf(h.z, wb.z, acc[i][1]);
                acc[i][1] = fmaf(h.w, wb.w, acc[i][1]);
            }
        }
    }

    // per-thread stats + max/min over owned rows
    float s0 = 0.f, q0 = 0.f, s1 = 0.f, q1 = 0.f;
    float mx0 = -3.4e38f, mn0 = 3.4e38f, mx1 = -3.4e38f, mn1 = 3.4e38f;
#pragma unroll
    for (int i = 0; i < NPW; i++) {
        float a = acc[i][0], b = acc[i][1];
        s0 += a; q0 = fmaf(a, a, q0);
        s1 += b; q1 = fmaf(b, b, q1);
        mx0 = fmaxf(mx0, a); mn0 = fminf(mn0, a);
        mx1 = fmaxf(mx1, b); mn1 = fminf(mn1, b);
    }
    sred[wv*128 + o0] = s0; sred[wv*128 + o1] = s1;
    qred[wv*128 + o0] = q0; qred[wv*128 + o1] = q1;
    __syncthreads();
    if (wv == 0) {
        float ssa = 0.f, ssb = 0.f, qqa = 0.f, qqb = 0.f;
#pragma unroll
        for (int r = 0; r < 8; r++) {
            ssa += sred[r*128 + o0]; ssb += sred[r*128 + o1];
            qqa += qred[r*128 + o0]; qqb += qred[r*128 + o1];
        }
        atomicAdd(&s2sum[o0], ssa); atomicAdd(&s2sq[o0], qqa);
        atomicAdd(&s2sum[o1], ssb); atomicAdd(&s2sq[o1], qqb);
    }
    __syncthreads();
    sred[wv*128 + o0] = mx0; sred[wv*128 + o1] = mx1;
    qred[wv*128 + o0] = mn0; qred[wv*128 + o1] = mn1;
    __syncthreads();
    if (wv == 0) {
        float Ma = -3.4e38f, Mb = -3.4e38f, Na = 3.4e38f, Nb = 3.4e38f;
#pragma unroll
        for (int r = 0; r < 8; r++) {
            Ma = fmaxf(Ma, sred[r*128 + o0]); Mb = fmaxf(Mb, sred[r*128 + o1]);
            Na = fminf(Na, qred[r*128 + o0]); Nb = fminf(Nb, qred[r*128 + o1]);
        }
        mxo[m*128 + o0] = Ma; mxo[m*128 + o1] = Mb;
        mno[m*128 + o0] = Na; mno[m*128 + o1] = Nb;
    }
}

// ---------------------------------------------------------------------------
// Pass 3 (tiny): out = relu(k2 * (k2>=0 ? max : min) + sh2) per (m, o).
// ---------------------------------------------------------------------------
__global__ void __launch_bounds__(256, 1) sa_pass3(
    const float* __restrict__ mxo, const float* __restrict__ mno,
    const float* __restrict__ g1, const float* __restrict__ b1,
    const float* __restrict__ s2sum, const float* __restrict__ s2sq,
    float* __restrict__ outp, float invN)
{
    int i = blockIdx.x * 256 + threadIdx.x;
    if (i >= MTOT*128) return;
    int m = i >> 7, o = i & 127;
    float mean = s2sum[o] * invN;
    float var  = s2sq[o] * invN - mean * mean;
    float k    = rsqrtf(var + 1e-5f) * g1[o];
    float sh   = b1[o] - mean * k;
    float v    = (k >= 0.f) ? mxo[i] : mno[i];
    float r    = fmaf(v, k, sh);
    outp[(long long)m*256 + o] = r > 0.f ? r : 0.f;
}

// ---------------------------------------------------------------------------
extern "C" void kernel_launch(void* const* d_in, const int* in_sizes, int n_in,
                              void* d_out, int out_size, void* d_ws, size_t ws_size,
                              hipStream_t stream)
{
    const float* xyz  = (const float*)d_in[0];
    const float* feat = (const float*)d_in[1];
    const float* nxyz = (const float*)d_in[2];
    const float* w00 = (const float*)d_in[5];
    const float* g00 = (const float*)d_in[6];
    const float* b00 = (const float*)d_in[7];
    const float* w01 = (const float*)d_in[8];
    const float* g01 = (const float*)d_in[9];
    const float* b01 = (const float*)d_in[10];
    const float* w10 = (const float*)d_in[11];
    const float* g10 = (const float*)d_in[12];
    const float* b10 = (const float*)d_in[13];
    const float* w11 = (const float*)d_in[14];
    const float* g11 = (const float*)d_in[15];
    const float* b11 = (const float*)d_in[16];
    float* out = (float*)d_out;

    // ws: stats | idx0 | idx1 | empty0/1 | x1 (134 MB) | mx/mn per scale
    char*  wsb    = (char*)d_ws;
    float* stats  = (float*)(wsb);
    int*   idx0   = (int*)(wsb + 4096);
    int*   idx1   = (int*)(wsb + 4096 + 524288);
    int*   empty0 = (int*)(wsb + 4096 + 524288 + 1048576);
    int*   empty1 = (int*)(wsb + 4096 + 524288 + 1048576 + 32768);
    float* x      = (float*)(wsb + 4096 + 524288 + 1048576 + 65536);
    float* mx0    = (float*)(wsb + 150000000);
    float* mn0    = (float*)(wsb + 155000000);
    float* mx1    = (float*)(wsb + 160000000);
    float* mn1    = (float*)(wsb + 165000000);

    StackSAModuleMSG_85761906966880_kernel<<<96, 256, 0, stream>>>(nxyz, out, stats);
    sa_ballq<<<MTOT, 64, 0, stream>>>(xyz, nxyz, idx0, idx1, empty0, empty1);

    float* fout = out + MTOT*3;
    const float invN0 = 1.0f / (float)(MTOT*16);
    const float invN1 = 1.0f / (float)(MTOT*32);
    const int P3B = (MTOT*128 + 255) / 256;

    // scale 0 (r=0.2, ns=16)  NPW = 2
    sa_pass1<2><<<MTOT, 512, 0, stream>>>(xyz, feat, nxyz, idx0, empty0, w00,
                                          x, stats + 0, stats + 128);
    sa_pass2<2><<<MTOT, 512, 0, stream>>>(x, w01, g00, b00, stats + 0, stats + 128,
                                          stats + 256, stats + 384, mx0, mn0, invN0);
    sa_pass3<<<P3B, 256, 0, stream>>>(mx0, mn0, g01, b01, stats + 256, stats + 384,
                                      fout, invN0);
    // scale 1 (r=0.4, ns=32)  NPW = 4
    sa_pass1<4><<<MTOT, 512, 0, stream>>>(xyz, feat, nxyz, idx1, empty1, w10,
                                          x, stats + 512, stats + 640);
    sa_pass2<4><<<MTOT, 512, 0, stream>>>(x, w11, g10, b10, stats + 512, stats + 640,
                                          stats + 768, stats + 896, mx1, mn1, invN1);
    sa_pass3<<<P3B, 256, 0, stream>>>(mx1, mn1, g11, b11, stats + 768, stats + 896,
                                      fout + 128, invN1);

    hipError_t e = hipGetLastError();
    if (e != hipSuccess) EPR("[KL] enqueue err=%d (%s)\n", (int)e, hipGetErrorString(e));
}

// Round 18
// 703.761 us; speedup vs baseline: 2.1063x; 1.4555x over previous
//
#include <hip/hip_runtime.h>
#include <stdio.h>

#define NBP   8192
#define MTOT  8192
#define CIN   64
#define CO    128

#define EPR(...) do { fprintf(stderr, __VA_ARGS__); fflush(stderr); } while (0)

// ---------------------------------------------------------------------------
// Zero the 1024-float BN-stats region; write output 0 = new_xyz (f32 copy).
// ---------------------------------------------------------------------------
__global__ void __launch_bounds__(256, 1) StackSAModuleMSG_85761906966880_kernel(
    const float* __restrict__ nxyz, float* __restrict__ out, float* __restrict__ stats)
{
    int i = blockIdx.x * 256 + threadIdx.x;
    if (i < 1024) stats[i] = 0.f;
    if (i < MTOT*3) out[i] = nxyz[i];
}

// ---------------------------------------------------------------------------
// Ball query, both scales: one wave per query; f64 d2 (matches np gold).
// ---------------------------------------------------------------------------
__global__ void __launch_bounds__(64, 1) sa_ballq(
    const float* __restrict__ xyz, const float* __restrict__ new_xyz,
    int* __restrict__ idx0, int* __restrict__ idx1,
    int* __restrict__ empty0, int* __restrict__ empty1)
{
    const double r2a = 0.2 * 0.2;
    const double r2b = 0.4 * 0.4;
    int m    = blockIdx.x;
    int lane = threadIdx.x;
    int b    = m >> 11;
    int base = b * NBP;

    double nx = (double)new_xyz[3*m+0];
    double ny = (double)new_xyz[3*m+1];
    double nz = (double)new_xyz[3*m+2];
    double nn = nx*nx + ny*ny + nz*nz;

    int cnt0 = 0, cnt1 = 0;
    int first0 = base, first1 = base;
    unsigned long long lt = (1ull << lane) - 1ull;

    for (int j = 0; j < NBP; j += 64) {
        int gi = base + j + lane;
        double px = (double)xyz[3*gi+0];
        double py = (double)xyz[3*gi+1];
        double pz = (double)xyz[3*gi+2];
        double pp = px*px + py*py + pz*pz;
        double dt = nx*px + ny*py + nz*pz;
        double d2 = nn + pp - 2.0*dt;
        bool in0 = d2 < r2a;
        bool in1 = d2 < r2b;
        unsigned long long m0 = __ballot(in0);
        unsigned long long m1 = __ballot(in1);
        if (in0) {
            int p = cnt0 + __popcll(m0 & lt);
            if (p < 16) idx0[m*16 + p] = gi;
        }
        if (in1) {
            int p = cnt1 + __popcll(m1 & lt);
            if (p < 32) idx1[m*32 + p] = gi;
        }
        if (cnt0 == 0 && m0) first0 = base + j + (__ffsll((long long)m0) - 1);
        if (cnt1 == 0 && m1) first1 = base + j + (__ffsll((long long)m1) - 1);
        cnt0 += __popcll(m0);
        cnt1 += __popcll(m1);
        if (cnt0 >= 16 && cnt1 >= 32) break;
    }
    int c0 = cnt0 < 16 ? cnt0 : 16;
    int c1 = cnt1 < 32 ? cnt1 : 32;
    if (lane >= c0 && lane < 16) idx0[m*16 + lane] = first0;
    if (lane >= c1 && lane < 32) idx1[m*32 + lane] = first1;
    if (lane == 0) { empty0[m] = (cnt0 == 0); empty1[m] = (cnt1 == 0); }
}

// ---------------------------------------------------------------------------
// Pass 1: LDS-tiled GEMM over MB=2 query groups per block (ROWS = 2*NS).
// 256 thr = 4 waves; lane owns cols {li, li+32, li+64, li+96}; lane-half
// owns RH = NS/4 rows. Per q: 4 w-reads + RH h-reads -> 16*RH FMA instrs.
// ---------------------------------------------------------------------------
template<int NS>
__global__ void __launch_bounds__(256, 2) sa_pass1(
    const float* __restrict__ xyz, const float* __restrict__ feat,
    const float* __restrict__ nxyz, const int* __restrict__ idx,
    const int* __restrict__ empty, const float* __restrict__ w0,
    float* __restrict__ x1, float* __restrict__ ssum, float* __restrict__ ssq)
{
    const int ROWS = 2*NS;
    const int RH   = NS/4;
    __shared__ float gs[ROWS*68];
    __shared__ float ws[128*68];
    __shared__ float sred[8*128];
    __shared__ float qred[8*128];
    __shared__ int   lidx[64];
    int bx = blockIdx.x, t = threadIdx.x;
    int m0 = 2*bx;
    int wv = t >> 6, L = t & 63, hf = L >> 5, li = L & 31;

    if (t < ROWS) lidx[t] = idx[(long long)m0*NS + t];   // groups contiguous
    __syncthreads();
    int emp0 = empty[m0], emp1 = empty[m0+1];
    for (int e = t; e < ROWS*68; e += 256) {
        int n = e / 68, c = e - n*68;
        int g = (n >= NS);
        float v = 0.f;
        if (c < 67 && !(g ? emp1 : emp0)) {
            int gi = lidx[n];
            int mq = m0 + g;
            v = (c < 3) ? (xyz[3*gi+c] - nxyz[3*mq+c])
                        : feat[(long long)gi*CIN + (c-3)];
        }
        gs[e] = v;
    }
    for (int e = t; e < 128*68; e += 256) {
        int o = e / 68, k = e - o*68;
        ws[e] = (k < 67) ? w0[o*67 + k] : 0.f;
    }
    __syncthreads();

    float acc[RH][4];
#pragma unroll
    for (int i = 0; i < RH; i++)
        { acc[i][0]=0.f; acc[i][1]=0.f; acc[i][2]=0.f; acc[i][3]=0.f; }
    int c0 = li, c1 = li+32, c2 = li+64, c3 = li+96;
    int r0 = wv*(NS/2) + hf*RH;

    for (int q = 0; q < 17; q++) {
        int k = 4*q;
        float4 w0v = *(const float4*)(ws + c0*68 + k);
        float4 w1v = *(const float4*)(ws + c1*68 + k);
        float4 w2v = *(const float4*)(ws + c2*68 + k);
        float4 w3v = *(const float4*)(ws + c3*68 + k);
#pragma unroll
        for (int i = 0; i < RH; i++) {
            float4 g = *(const float4*)(gs + (r0+i)*68 + k);
            acc[i][0]=fmaf(g.x,w0v.x,acc[i][0]); acc[i][0]=fmaf(g.y,w0v.y,acc[i][0]);
            acc[i][0]=fmaf(g.z,w0v.z,acc[i][0]); acc[i][0]=fmaf(g.w,w0v.w,acc[i][0]);
            acc[i][1]=fmaf(g.x,w1v.x,acc[i][1]); acc[i][1]=fmaf(g.y,w1v.y,acc[i][1]);
            acc[i][1]=fmaf(g.z,w1v.z,acc[i][1]); acc[i][1]=fmaf(g.w,w1v.w,acc[i][1]);
            acc[i][2]=fmaf(g.x,w2v.x,acc[i][2]); acc[i][2]=fmaf(g.y,w2v.y,acc[i][2]);
            acc[i][2]=fmaf(g.z,w2v.z,acc[i][2]); acc[i][2]=fmaf(g.w,w2v.w,acc[i][2]);
            acc[i][3]=fmaf(g.x,w3v.x,acc[i][3]); acc[i][3]=fmaf(g.y,w3v.y,acc[i][3]);
            acc[i][3]=fmaf(g.z,w3v.z,acc[i][3]); acc[i][3]=fmaf(g.w,w3v.w,acc[i][3]);
        }
    }

    long long gbase = (long long)m0*NS*CO;
    float s[4] = {0,0,0,0}, qv[4] = {0,0,0,0};
#pragma unroll
    for (int i = 0; i < RH; i++) {
        long long rb = gbase + (long long)(r0+i)*CO;
        x1[rb+c0]=acc[i][0]; x1[rb+c1]=acc[i][1];
        x1[rb+c2]=acc[i][2]; x1[rb+c3]=acc[i][3];
#pragma unroll
        for (int j = 0; j < 4; j++) {
            s[j] += acc[i][j]; qv[j] = fmaf(acc[i][j], acc[i][j], qv[j]);
        }
    }
    int p = wv*2 + hf;
    sred[p*128+c0]=s[0]; sred[p*128+c1]=s[1]; sred[p*128+c2]=s[2]; sred[p*128+c3]=s[3];
    qred[p*128+c0]=qv[0]; qred[p*128+c1]=qv[1]; qred[p*128+c2]=qv[2]; qred[p*128+c3]=qv[3];
    __syncthreads();
    if (t < 128) {
        float ss = 0.f, qq = 0.f;
#pragma unroll
        for (int r = 0; r < 8; r++) { ss += sred[r*128+t]; qq += qred[r*128+t]; }
        atomicAdd(&ssum[t], ss); atomicAdd(&ssq[t], qq);
    }
}

// ---------------------------------------------------------------------------
// Pass 2: LDS-tiled GEMM, MB=2 groups/block. h = relu(BN1(x1)) -> LDS; W1 in
// two 64-k chunks; x2 kept in registers; emits per-(m,o) max/min + stats2.
// Waves 0,1 -> group m0 rows; waves 2,3 -> group m0+1 (no lane straddles).
// ---------------------------------------------------------------------------
template<int NS>
__global__ void __launch_bounds__(256, 2) sa_pass2(
    const float* __restrict__ x1, const float* __restrict__ w1,
    const float* __restrict__ g0, const float* __restrict__ b0,
    const float* __restrict__ s1sum, const float* __restrict__ s1sq,
    float* __restrict__ s2sum, float* __restrict__ s2sq,
    float* __restrict__ mxo, float* __restrict__ mno, float invN)
{
    const int ROWS = 2*NS;
    const int RH   = NS/4;
    __shared__ float hs[ROWS*128];
    __shared__ float wsc[128*68];
    __shared__ float kv[128], sv[128];
    __shared__ float sred[8*128];
    __shared__ float qred[8*128];
    int bx = blockIdx.x, t = threadIdx.x;
    int m0 = 2*bx;
    int wv = t >> 6, L = t & 63, hf = L >> 5, li = L & 31;

    if (t < 128) {
        float mean = s1sum[t] * invN;
        float var  = s1sq[t] * invN - mean * mean;
        float k    = rsqrtf(var + 1e-5f) * g0[t];
        kv[t] = k;
        sv[t] = b0[t] - mean * k;
    }
    __syncthreads();

    long long gbase = (long long)m0*NS*CO;
    for (int e = t; e < ROWS*32; e += 256) {    // float4 units
        int n = e >> 5, c4 = e & 31;
        float4 v  = *(const float4*)(x1 + gbase + (long long)n*CO + 4*c4);
        float4 kk = *(const float4*)(kv + 4*c4);
        float4 ss = *(const float4*)(sv + 4*c4);
        v.x = fmaxf(fmaf(v.x, kk.x, ss.x), 0.f);
        v.y = fmaxf(fmaf(v.y, kk.y, ss.y), 0.f);
        v.z = fmaxf(fmaf(v.z, kk.z, ss.z), 0.f);
        v.w = fmaxf(fmaf(v.w, kk.w, ss.w), 0.f);
        *(float4*)(hs + n*128 + 4*c4) = v;
    }

    float acc[RH][4];
#pragma unroll
    for (int i = 0; i < RH; i++)
        { acc[i][0]=0.f; acc[i][1]=0.f; acc[i][2]=0.f; acc[i][3]=0.f; }
    int c0 = li, c1 = li+32, c2 = li+64, c3 = li+96;
    int r0 = wv*(NS/2) + hf*RH;

    for (int ch = 0; ch < 2; ch++) {
        __syncthreads();   // hs ready (ch0) / previous wsc consumed (ch1)
        for (int e = t; e < 128*16; e += 256) { // float4 units
            int o = e >> 4, k4 = e & 15;
            *(float4*)(wsc + o*68 + 4*k4) =
                *(const float4*)(w1 + o*CO + ch*64 + 4*k4);
        }
        __syncthreads();
        for (int q = 0; q < 16; q++) {
            int k  = 4*q;
            int kh = ch*64 + k;
            float4 w0v = *(const float4*)(wsc + c0*68 + k);
            float4 w1v = *(const float4*)(wsc + c1*68 + k);
            float4 w2v = *(const float4*)(wsc + c2*68 + k);
            float4 w3v = *(const float4*)(wsc + c3*68 + k);
#pragma unroll
            for (int i = 0; i < RH; i++) {
                float4 h = *(const float4*)(hs + (r0+i)*128 + kh);
                acc[i][0]=fmaf(h.x,w0v.x,acc[i][0]); acc[i][0]=fmaf(h.y,w0v.y,acc[i][0]);
                acc[i][0]=fmaf(h.z,w0v.z,acc[i][0]); acc[i][0]=fmaf(h.w,w0v.w,acc[i][0]);
                acc[i][1]=fmaf(h.x,w1v.x,acc[i][1]); acc[i][1]=fmaf(h.y,w1v.y,acc[i][1]);
                acc[i][1]=fmaf(h.z,w1v.z,acc[i][1]); acc[i][1]=fmaf(h.w,w1v.w,acc[i][1]);
                acc[i][2]=fmaf(h.x,w2v.x,acc[i][2]); acc[i][2]=fmaf(h.y,w2v.y,acc[i][2]);
                acc[i][2]=fmaf(h.z,w2v.z,acc[i][2]); acc[i][2]=fmaf(h.w,w2v.w,acc[i][2]);
                acc[i][3]=fmaf(h.x,w3v.x,acc[i][3]); acc[i][3]=fmaf(h.y,w3v.y,acc[i][3]);
                acc[i][3]=fmaf(h.z,w3v.z,acc[i][3]); acc[i][3]=fmaf(h.w,w3v.w,acc[i][3]);
            }
        }
    }

    float s[4] = {0,0,0,0}, qv[4] = {0,0,0,0};
    float mx[4] = {-3.4e38f,-3.4e38f,-3.4e38f,-3.4e38f};
    float mn[4] = { 3.4e38f, 3.4e38f, 3.4e38f, 3.4e38f};
#pragma unroll
    for (int i = 0; i < RH; i++) {
#pragma unroll
        for (int j = 0; j < 4; j++) {
            float a = acc[i][j];
            s[j] += a; qv[j] = fmaf(a, a, qv[j]);
            mx[j] = fmaxf(mx[j], a); mn[j] = fminf(mn[j], a);
        }
    }
    int p = wv*2 + hf;
    sred[p*128+c0]=s[0]; sred[p*128+c1]=s[1]; sred[p*128+c2]=s[2]; sred[p*128+c3]=s[3];
    qred[p*128+c0]=qv[0]; qred[p*128+c1]=qv[1]; qred[p*128+c2]=qv[2]; qred[p*128+c3]=qv[3];
    __syncthreads();
    if (t < 128) {
        float ss = 0.f, qq = 0.f;
#pragma unroll
        for (int r = 0; r < 8; r++) { ss += sred[r*128+t]; qq += qred[r*128+t]; }
        atomicAdd(&s2sum[t], ss); atomicAdd(&s2sq[t], qq);
    }
    __syncthreads();
    sred[p*128+c0]=mx[0]; sred[p*128+c1]=mx[1]; sred[p*128+c2]=mx[2]; sred[p*128+c3]=mx[3];
    qred[p*128+c0]=mn[0]; qred[p*128+c1]=mn[1]; qred[p*128+c2]=mn[2]; qred[p*128+c3]=mn[3];
    __syncthreads();
    if (t < 128) {
        float M0=-3.4e38f, N0=3.4e38f, M1=-3.4e38f, N1=3.4e38f;
#pragma unroll
        for (int r = 0; r < 4; r++) {               // partials p=0..3 -> m0
            M0 = fmaxf(M0, sred[r*128+t]); N0 = fminf(N0, qred[r*128+t]);
        }
#pragma unroll
        for (int r = 4; r < 8; r++) {               // partials p=4..7 -> m0+1
            M1 = fmaxf(M1, sred[r*128+t]); N1 = fminf(N1, qred[r*128+t]);
        }
        mxo[(long long)m0*128 + t]     = M0; mno[(long long)m0*128 + t]     = N0;
        mxo[(long long)(m0+1)*128 + t] = M1; mno[(long long)(m0+1)*128 + t] = N1;
    }
}

// ---------------------------------------------------------------------------
// Pass 3 (tiny): out = relu(k2 * (k2>=0 ? max : min) + sh2) per (m, o).
// ---------------------------------------------------------------------------
__global__ void __launch_bounds__(256, 1) sa_pass3(
    const float* __restrict__ mxo, const float* __restrict__ mno,
    const float* __restrict__ g1, const float* __restrict__ b1,
    const float* __restrict__ s2sum, const float* __restrict__ s2sq,
    float* __restrict__ outp, float invN)
{
    int i = blockIdx.x * 256 + threadIdx.x;
    if (i >= MTOT*128) return;
    int m = i >> 7, o = i & 127;
    float mean = s2sum[o] * invN;
    float var  = s2sq[o] * invN - mean * mean;
    float k    = rsqrtf(var + 1e-5f) * g1[o];
    float sh   = b1[o] - mean * k;
    float v    = (k >= 0.f) ? mxo[i] : mno[i];
    float r    = fmaf(v, k, sh);
    outp[(long long)m*256 + o] = r > 0.f ? r : 0.f;
}

// ---------------------------------------------------------------------------
extern "C" void kernel_launch(void* const* d_in, const int* in_sizes, int n_in,
                              void* d_out, int out_size, void* d_ws, size_t ws_size,
                              hipStream_t stream)
{
    const float* xyz  = (const float*)d_in[0];
    const float* feat = (const float*)d_in[1];
    const float* nxyz = (const float*)d_in[2];
    const float* w00 = (const float*)d_in[5];
    const float* g00 = (const float*)d_in[6];
    const float* b00 = (const float*)d_in[7];
    const float* w01 = (const float*)d_in[8];
    const float* g01 = (const float*)d_in[9];
    const float* b01 = (const float*)d_in[10];
    const float* w10 = (const float*)d_in[11];
    const float* g10 = (const float*)d_in[12];
    const float* b10 = (const float*)d_in[13];
    const float* w11 = (const float*)d_in[14];
    const float* g11 = (const float*)d_in[15];
    const float* b11 = (const float*)d_in[16];
    float* out = (float*)d_out;

    // ws: stats | idx0 | idx1 | empty0/1 | x1 (134 MB) | mx/mn per scale
    char*  wsb    = (char*)d_ws;
    float* stats  = (float*)(wsb);
    int*   idx0   = (int*)(wsb + 4096);
    int*   idx1   = (int*)(wsb + 4096 + 524288);
    int*   empty0 = (int*)(wsb + 4096 + 524288 + 1048576);
    int*   empty1 = (int*)(wsb + 4096 + 524288 + 1048576 + 32768);
    float* x      = (float*)(wsb + 4096 + 524288 + 1048576 + 65536);
    float* mx0    = (float*)(wsb + 150000000);
    float* mn0    = (float*)(wsb + 155000000);
    float* mx1    = (float*)(wsb + 160000000);
    float* mn1    = (float*)(wsb + 165000000);

    StackSAModuleMSG_85761906966880_kernel<<<96, 256, 0, stream>>>(nxyz, out, stats);
    sa_ballq<<<MTOT, 64, 0, stream>>>(xyz, nxyz, idx0, idx1, empty0, empty1);

    float* fout = out + MTOT*3;
    const float invN0 = 1.0f / (float)(MTOT*16);
    const float invN1 = 1.0f / (float)(MTOT*32);
    const int P3B = (MTOT*128 + 255) / 256;
    const int GB  = MTOT/2;   // 2 query groups per block

    // scale 0 (r=0.2, ns=16)
    sa_pass1<16><<<GB, 256, 0, stream>>>(xyz, feat, nxyz, idx0, empty0, w00,
                                         x, stats + 0, stats + 128);
    sa_pass2<16><<<GB, 256, 0, stream>>>(x, w01, g00, b00, stats + 0, stats + 128,
                                         stats + 256, stats + 384, mx0, mn0, invN0);
    sa_pass3<<<P3B, 256, 0, stream>>>(mx0, mn0, g01, b01, stats + 256, stats + 384,
                                      fout, invN0);
    // scale 1 (r=0.4, ns=32)
    sa_pass1<32><<<GB, 256, 0, stream>>>(xyz, feat, nxyz, idx1, empty1, w10,
                                         x, stats + 512, stats + 640);
    sa_pass2<32><<<GB, 256, 0, stream>>>(x, w11, g10, b10, stats + 512, stats + 640,
                                         stats + 768, stats + 896, mx1, mn1, invN1);
    sa_pass3<<<P3B, 256, 0, stream>>>(mx1, mn1, g11, b11, stats + 768, stats + 896,
                                      fout + 128, invN1);

    hipError_t e = hipGetLastError();
    if (e != hipSuccess) EPR("[KL] enqueue err=%d (%s)\n", (int)e, hipGetErrorString(e));
}